// Round 2
// baseline (1223.891 us; speedup 1.0000x reference)
//
#include <hip/hip_runtime.h>
#include <stdint.h>

#define DF 128
typedef unsigned short ushort_t;
typedef __attribute__((ext_vector_type(8))) short short8v;   // 8 bf16 (4 VGPRs)
typedef __attribute__((ext_vector_type(4))) float f32x4;

// ---------------- Threefry-2x32 (JAX-compatible, 20 rounds) ----------------
__host__ __device__ __forceinline__ unsigned rotl32(unsigned v, int r) {
  return (v << r) | (v >> (32 - r));
}

__host__ __device__ __forceinline__ void threefry2x32(
    unsigned k0, unsigned k1, unsigned c0, unsigned c1,
    unsigned& o0, unsigned& o1) {
  unsigned kx = k0 ^ k1 ^ 0x1BD11BDAu;
  unsigned x0 = c0 + k0;
  unsigned x1 = c1 + k1;
#define TF_R(r) { x0 += x1; x1 = rotl32(x1, r); x1 ^= x0; }
  TF_R(13) TF_R(15) TF_R(26) TF_R(6)
  x0 += k1; x1 += kx + 1u;
  TF_R(17) TF_R(29) TF_R(16) TF_R(24)
  x0 += kx; x1 += k0 + 2u;
  TF_R(13) TF_R(15) TF_R(26) TF_R(6)
  x0 += k0; x1 += k1 + 3u;
  TF_R(17) TF_R(29) TF_R(16) TF_R(24)
  x0 += k1; x1 += kx + 4u;
  TF_R(13) TF_R(15) TF_R(26) TF_R(6)
  x0 += kx; x1 += k0 + 5u;
#undef TF_R
  o0 = x0; o1 = x1;
}

#define KEEP_THR 0xE6666600u   // uniform(bits) < 0.9f

// ---------------- bf16 helpers (RTNE) --------------------------------------
__device__ __forceinline__ ushort_t f2bf(float f) {
  unsigned u = __float_as_uint(f);
  unsigned r = (u + 0x7fffu + ((u >> 16) & 1u)) >> 16;
  return (ushort_t)r;
}
__device__ __forceinline__ float bf2f(ushort_t h) {
  return __uint_as_float(((unsigned)h) << 16);
}

// ---------------- MFMA GEMM [M,128] x [128,128] ----------------------------
// EPI 0: outB = bf16(X@W1)
// EPI 1: outF = relu(X@W1 + bf2f(acc1)/max(cnt1,1))
// EPI 2: outF = relu(0.5*(X@(W1+W2) + acc1/n1 + acc2/n2))
// Block 256 = 4 waves; BM=128 (wave w: rows w*32..w*32+31, two 16-row groups).
// mfma_f32_16x16x32_bf16; C/D: col=lane&15, row=(lane>>4)*4+j (HW-verified).
// A/B k-map: k = (lane>>4)*8 + j applied symmetrically (permutation-safe).
template <int EPI>
__global__ __launch_bounds__(256) void gemm_mfma(
    const float* __restrict__ X, const float* __restrict__ W1,
    const float* __restrict__ W2, int M,
    ushort_t* __restrict__ outB, float* __restrict__ outF,
    const ushort_t* __restrict__ acc1, const unsigned* __restrict__ cnt1,
    const ushort_t* __restrict__ acc2, const unsigned* __restrict__ cnt2) {
  __shared__ ushort_t Wt[DF][136];   // W^T bf16, padded: row stride 272B (16B-mult)
  const int t = threadIdx.x;
  const int lane = t & 63;
  const int w = t >> 6;
  const int lr = lane & 15;     // A-row / B-col within 16
  const int kg = lane >> 4;     // k-group 0..3
  const int rbase = blockIdx.x * 128;

  // stage W (optionally W1+W2) transposed as bf16
#pragma unroll
  for (int i = 0; i < 16; ++i) {
    int q = t + i * 256;            // 0..4095 float4 index
    int k = q >> 5;                 // 0..127
    int c4 = (q & 31) * 4;
    float4 wv = *reinterpret_cast<const float4*>(&W1[k * DF + c4]);
    if constexpr (EPI == 2) {
      float4 w2 = *reinterpret_cast<const float4*>(&W2[k * DF + c4]);
      wv.x += w2.x; wv.y += w2.y; wv.z += w2.z; wv.w += w2.w;
    }
    Wt[c4 + 0][k] = f2bf(wv.x);
    Wt[c4 + 1][k] = f2bf(wv.y);
    Wt[c4 + 2][k] = f2bf(wv.z);
    Wt[c4 + 3][k] = f2bf(wv.w);
  }
  __syncthreads();

  f32x4 acc[2][8];
#pragma unroll
  for (int rg = 0; rg < 2; ++rg)
#pragma unroll
    for (int n = 0; n < 8; ++n) acc[rg][n] = (f32x4){0.f, 0.f, 0.f, 0.f};

#pragma unroll
  for (int kt = 0; kt < 4; ++kt) {
    const int kb = kt * 32 + kg * 8;
    short8v a[2];
#pragma unroll
    for (int rg = 0; rg < 2; ++rg) {
      int r = rbase + w * 32 + rg * 16 + lr;
      float4 x0 = make_float4(0.f, 0.f, 0.f, 0.f);
      float4 x1 = x0;
      if (r < M) {
        x0 = *reinterpret_cast<const float4*>(&X[(size_t)r * DF + kb]);
        x1 = *reinterpret_cast<const float4*>(&X[(size_t)r * DF + kb + 4]);
      }
      short8v av;
      av[0] = (short)f2bf(x0.x); av[1] = (short)f2bf(x0.y);
      av[2] = (short)f2bf(x0.z); av[3] = (short)f2bf(x0.w);
      av[4] = (short)f2bf(x1.x); av[5] = (short)f2bf(x1.y);
      av[6] = (short)f2bf(x1.z); av[7] = (short)f2bf(x1.w);
      a[rg] = av;
    }
#pragma unroll
    for (int n = 0; n < 8; ++n) {
      short8v b = *reinterpret_cast<const short8v*>(&Wt[n * 16 + lr][kb]);
#pragma unroll
      for (int rg = 0; rg < 2; ++rg)
        acc[rg][n] = __builtin_amdgcn_mfma_f32_16x16x32_bf16(a[rg], b, acc[rg][n], 0, 0, 0);
    }
  }

  // epilogue
#pragma unroll
  for (int rg = 0; rg < 2; ++rg) {
    const int rb = rbase + w * 32 + rg * 16 + kg * 4;
    float inv1[4], inv2[4];
    if (EPI >= 1) {
#pragma unroll
      for (int j = 0; j < 4; ++j)
        inv1[j] = (rb + j < M) ? 1.0f / fmaxf((float)cnt1[rb + j], 1.0f) : 1.0f;
    }
    if (EPI == 2) {
#pragma unroll
      for (int j = 0; j < 4; ++j)
        inv2[j] = (rb + j < M) ? 1.0f / fmaxf((float)cnt2[rb + j], 1.0f) : 1.0f;
    }
#pragma unroll
    for (int n = 0; n < 8; ++n) {
      const int col = n * 16 + lr;
#pragma unroll
      for (int j = 0; j < 4; ++j) {
        const int r = rb + j;
        if (r < M) {
          float vv = acc[rg][n][j];
          if (EPI == 0) {
            outB[(size_t)r * DF + col] = f2bf(vv);
          } else if (EPI == 1) {
            float a1 = bf2f(acc1[(size_t)r * DF + col]);
            outF[(size_t)r * DF + col] = fmaxf(vv + a1 * inv1[j], 0.f);
          } else {
            float a1 = bf2f(acc1[(size_t)r * DF + col]);
            float a2 = bf2f(acc2[(size_t)r * DF + col]);
            outF[(size_t)r * DF + col] =
                fmaxf(0.5f * (vv + a1 * inv1[j] + a2 * inv2[j]), 0.f);
          }
        }
      }
    }
  }
}

// ------------- per-edge gather + dropout + pk-bf16 scatter-add -------------
// 16 lanes/edge, 8 features/lane: one 16B gather, 8 interleaved threefrys,
// 4 packed-bf16 atomics. bits(l) = o0^o1 of threefry(key,(0,l)), l=e*128+d.
__global__ __launch_bounds__(256) void scatter_pk(
    const ushort_t* __restrict__ proj, const int* __restrict__ src,
    const int* __restrict__ dst, ushort_t* __restrict__ accum,
    unsigned* __restrict__ cnt, int E, unsigned k0, unsigned k1) {
  const int t = threadIdx.x;
  const int e = blockIdx.x * 16 + (t >> 4);
  if (e >= E) return;
  const int g16 = t & 15;
  const int d0 = g16 * 8;
  const int s = src[e];
  const int dd = dst[e];
  if (g16 == 0) atomicAdd(&cnt[dd], 1u);

  const uint4 g = *reinterpret_cast<const uint4*>(proj + (size_t)s * DF + d0);
  const unsigned gw[4] = {g.x, g.y, g.z, g.w};
  const unsigned base = (unsigned)e * 128u + (unsigned)d0;

  float v[8];
  unsigned keep = 0;
#pragma unroll
  for (int j = 0; j < 8; ++j) {
    unsigned o0, o1;
    threefry2x32(k0, k1, 0u, base + j, o0, o1);
    unsigned bits = o0 ^ o1;
    unsigned raw = (j & 1) ? (gw[j >> 1] >> 16) : (gw[j >> 1] & 0xffffu);
    float f = __uint_as_float(raw << 16) * (1.0f / 0.9f);
    bool kp = bits < KEEP_THR;
    v[j] = kp ? f : 0.0f;
    keep |= ((unsigned)kp) << j;
  }

  ushort_t* ap = accum + (size_t)dd * DF + d0;
#pragma unroll
  for (int p = 0; p < 4; ++p) {
    if (keep & (3u << (2 * p))) {
      unsigned pk = ((unsigned)f2bf(v[2 * p])) | (((unsigned)f2bf(v[2 * p + 1])) << 16);
      uint64_t addr = (uint64_t)(ap + 2 * p);
      asm volatile("global_atomic_pk_add_bf16 %0, %1, off"
                   :: "v"(addr), "v"(pk) : "memory");
    }
  }
}

// ---------------------------------------------------------------------------
extern "C" void kernel_launch(void* const* d_in, const int* in_sizes, int n_in,
                              void* d_out, int out_size, void* d_ws, size_t ws_size,
                              hipStream_t stream) {
  const float* x_user      = (const float*)d_in[0];
  const float* x_spot      = (const float*)d_in[1];
  const float* W_visit_src = (const float*)d_in[2];
  const float* W_visit_tgt = (const float*)d_in[3];
  const float* W_rev_src   = (const float*)d_in[4];
  const float* W_rev_tgt   = (const float*)d_in[5];
  const float* W_near_src  = (const float*)d_in[6];
  const float* W_near_tgt  = (const float*)d_in[7];
  const int* visit_src = (const int*)d_in[8];
  const int* visit_dst = (const int*)d_in[9];
  const int* rev_src   = (const int*)d_in[10];
  const int* rev_dst   = (const int*)d_in[11];
  const int* near_src  = (const int*)d_in[12];
  const int* near_dst  = (const int*)d_in[13];

  const int n_user = in_sizes[0] / DF;
  const int n_spot = in_sizes[1] / DF;
  const int e_visit = in_sizes[8];
  const int e_rev   = in_sizes[10];
  const int e_near  = in_sizes[12];

  float* out_user = (float*)d_out;
  float* out_spot = out_user + (size_t)n_user * DF;

  // workspace: bf16 proj/accum. accum_u aliases proj_vs, accum_sn aliases
  // proj_rs (each proj dead before its alias is zeroed, stream-ordered).
  char* ws = (char*)d_ws;
  size_t off = 0;
  auto alloc = [&](size_t bytes) -> void* {
    void* p = ws + off;
    off += (bytes + 255) & ~(size_t)255;
    return p;
  };
  ushort_t* proj_vs  = (ushort_t*)alloc((size_t)n_user * DF * 2);
  ushort_t* proj_rs  = (ushort_t*)alloc((size_t)n_spot * DF * 2);
  ushort_t* proj_ns  = (ushort_t*)alloc((size_t)n_spot * DF * 2);
  ushort_t* accum_sv = (ushort_t*)alloc((size_t)n_spot * DF * 2);
  unsigned* cnt_u  = (unsigned*)alloc((size_t)n_user * 4);
  unsigned* cnt_sv = (unsigned*)alloc((size_t)n_spot * 4);
  unsigned* cnt_sn = (unsigned*)alloc((size_t)n_spot * 4);
  char* region_end = ws + off;
  ushort_t* accum_u  = proj_vs;
  ushort_t* accum_sn = proj_rs;

  // dropout keys: fold_in(key(1), t) == threefry((0,1),(0,t))
  unsigned kv0, kv1, kr0, kr1, kn0, kn1;
  threefry2x32(0u, 1u, 0u, 0u, kv0, kv1);
  threefry2x32(0u, 1u, 0u, 1u, kr0, kr1);
  threefry2x32(0u, 1u, 0u, 2u, kn0, kn1);

  dim3 blk(256);
  const int gb_user = (n_user + 127) / 128;
  const int gb_spot = (n_spot + 127) / 128;

  // source-side projections (bf16 outputs)
  gemm_mfma<0><<<gb_user, blk, 0, stream>>>(x_user, W_visit_src, nullptr, n_user,
                                            proj_vs, nullptr, nullptr, nullptr,
                                            nullptr, nullptr);
  gemm_mfma<0><<<gb_spot, blk, 0, stream>>>(x_spot, W_rev_src, nullptr, n_spot,
                                            proj_rs, nullptr, nullptr, nullptr,
                                            nullptr, nullptr);
  gemm_mfma<0><<<gb_spot, blk, 0, stream>>>(x_spot, W_near_src, nullptr, n_spot,
                                            proj_ns, nullptr, nullptr, nullptr,
                                            nullptr, nullptr);

  // zero accum_sv + all three count arrays (contiguous)
  hipMemsetAsync(accum_sv, 0, (size_t)(region_end - (char*)accum_sv), stream);

  // visit: user -> spot
  scatter_pk<<<(e_visit + 15) / 16, blk, 0, stream>>>(
      proj_vs, visit_src, visit_dst, accum_sv, cnt_sv, e_visit, kv0, kv1);

  // rev: spot -> user (accum_u reuses proj_vs storage)
  hipMemsetAsync(accum_u, 0, (size_t)n_user * DF * 2, stream);
  scatter_pk<<<(e_rev + 15) / 16, blk, 0, stream>>>(
      proj_rs, rev_src, rev_dst, accum_u, cnt_u, e_rev, kr0, kr1);

  // near: spot -> spot (accum_sn reuses proj_rs storage)
  hipMemsetAsync(accum_sn, 0, (size_t)n_spot * DF * 2, stream);
  scatter_pk<<<(e_near + 15) / 16, blk, 0, stream>>>(
      proj_ns, near_src, near_dst, accum_sn, cnt_sn, e_near, kn0, kn1);

  // finalize: fused tgt-projection + mean + relu
  gemm_mfma<1><<<gb_user, blk, 0, stream>>>(x_user, W_rev_tgt, nullptr, n_user,
                                            nullptr, out_user, accum_u, cnt_u,
                                            nullptr, nullptr);
  gemm_mfma<2><<<gb_spot, blk, 0, stream>>>(x_spot, W_visit_tgt, W_near_tgt, n_spot,
                                            nullptr, out_spot, accum_sv, cnt_sv,
                                            accum_sn, cnt_sn);
}